// Round 1
// baseline (24.803 us; speedup 1.0000x reference)
//
#include <hip/hip_runtime.h>
#include <math.h>

#define NN 256
#define PP 32640   // N*(N-1)/2
#define HH 64

// One block per batch element. Threads scan dec/ind rows (float4, coalesced),
// build an LDS degree histogram of accepted pairs (dec==1), find the one-hot
// index `cur`, then a tiny matvec chain produces the two (equal) sigmoid outputs.
//
// Key algebraic collapse: the GCN graph is the complete digraph + self loops,
// so norm = 1/256 everywhere and every conv output is node-independent:
//   conv(h)[b,v] = (1/256) * sum_u (h[b,u] @ W) + bias   (same for all v)
// => after conv1 h is constant across nodes; convs 2/3 are 64x64 matvecs.
// Only pair `cur` feeds the readout; both of its directed edges share rep.
__global__ __launch_bounds__(1024) void gnn_kernel(
    const float* __restrict__ x,
    const float* __restrict__ W1, const float* __restrict__ b1,
    const float* __restrict__ W2, const float* __restrict__ b2,
    const float* __restrict__ W3, const float* __restrict__ b3,
    const float* __restrict__ We1, const float* __restrict__ be1,
    const float* __restrict__ We2, const float* __restrict__ be2,
    float* __restrict__ out)
{
    const int b   = blockIdx.x;
    const int tid = threadIdx.x;

    __shared__ int   deg[NN];
    __shared__ int   s_cur;
    __shared__ int   s_sumdeg, s_cntzero;
    __shared__ float g1[HH], g2[HH], g3[HH];

    if (tid < NN) deg[tid] = 0;
    if (tid == 0) { s_cur = 0; s_sumdeg = 0; s_cntzero = 0; }
    __syncthreads();

    const float*  decp = x + (size_t)b * (2 * PP);
    const float*  indp = decp + PP;
    const float4* dec4 = (const float4*)decp;
    const float4* ind4 = (const float4*)indp;

    // P/4 = 8160 float4s per row
    for (int q = tid; q < PP / 4; q += blockDim.x) {
        float4 d  = dec4[q];
        float4 iv = ind4[q];
        float dv[4]  = {d.x, d.y, d.z, d.w};
        float ivv[4] = {iv.x, iv.y, iv.z, iv.w};
        #pragma unroll
        for (int u = 0; u < 4; ++u) {
            int p = q * 4 + u;
            if (ivv[u] > 0.5f) s_cur = p;   // exactly one per row (one-hot)
            if (dv[u] == 1.0f) {
                // invert triu_indices: find i with O(i) <= p < O(i+1),
                // O(i) = i*(511-i)/2 ; j = i+1 + (p - O(i))
                int i = (int)((511.0f - sqrtf(261121.0f - 8.0f * (float)p)) * 0.5f);
                while (i * (511 - i) / 2 > p) --i;
                while ((i + 1) * (510 - i) / 2 <= p) ++i;
                int j = i + 1 + (p - i * (511 - i) / 2);
                atomicAdd(&deg[i], 1);
                atomicAdd(&deg[j], 1);
            }
        }
    }
    __syncthreads();

    if (tid < NN) {
        int dv = deg[tid];
        atomicAdd(&s_sumdeg, dv);
        if (dv == 0) atomicAdd(&s_cntzero, 1);
    }
    __syncthreads();

    // Summed node features over all 256 nodes:
    //   f0 = sum(deg)/255,  f1 = #(deg==0),  f2 = sum(attached) = 2
    const float f0 = (float)s_sumdeg * (1.0f / 255.0f);
    const float f1 = (float)s_cntzero;
    const float f2 = 2.0f;

    if (tid < HH) {
        float s = f0 * W1[0 * HH + tid] + f1 * W1[1 * HH + tid] + f2 * W1[2 * HH + tid];
        s = s * (1.0f / 256.0f) + b1[tid];
        g1[tid] = fmaxf(s, 0.0f);
    }
    __syncthreads();

    if (tid < HH) {
        float s = b2[tid];
        #pragma unroll 8
        for (int k = 0; k < HH; ++k) s += g1[k] * W2[k * HH + tid];
        g2[tid] = fmaxf(s, 0.0f);
    }
    __syncthreads();

    if (tid < HH) {
        float s = b3[tid];
        #pragma unroll 8
        for (int k = 0; k < HH; ++k) s += g2[k] * W3[k * HH + tid];
        g3[tid] = fmaxf(s, 0.0f);
    }
    __syncthreads();

    if (tid < HH) {
        // current pair's edge features: [dec==1, dec!=0.5, ind(=1)]
        const float dcur = decp[s_cur];            // broadcast load
        const float e0 = (dcur == 1.0f) ? 1.0f : 0.0f;
        const float e1 = (dcur != 0.5f) ? 1.0f : 0.0f;

        float s = be1[tid];
        #pragma unroll 8
        for (int k = 0; k < HH; ++k)
            s += g3[k] * (We1[k * HH + tid] + We1[(HH + k) * HH + tid]);
        s += e0 * We1[128 * HH + tid] + e1 * We1[129 * HH + tid] + We1[130 * HH + tid];
        float hm = fmaxf(s, 0.0f);

        float contrib = hm * We2[tid];
        // threads 0..63 are exactly wave 0 (wave=64 on CDNA)
        #pragma unroll
        for (int off = 32; off > 0; off >>= 1)
            contrib += __shfl_down(contrib, off);

        if (tid == 0) {
            float logit = contrib + be2[0];
            float sig = 1.0f / (1.0f + expf(-logit));
            out[b * 2 + 0] = sig;
            out[b * 2 + 1] = sig;
        }
    }
}

extern "C" void kernel_launch(void* const* d_in, const int* in_sizes, int n_in,
                              void* d_out, int out_size, void* d_ws, size_t ws_size,
                              hipStream_t stream) {
    const float* x   = (const float*)d_in[0];
    const float* W1  = (const float*)d_in[1];
    const float* b1  = (const float*)d_in[2];
    const float* W2  = (const float*)d_in[3];
    const float* b2  = (const float*)d_in[4];
    const float* W3  = (const float*)d_in[5];
    const float* b3  = (const float*)d_in[6];
    const float* We1 = (const float*)d_in[7];
    const float* be1 = (const float*)d_in[8];
    const float* We2 = (const float*)d_in[9];
    const float* be2 = (const float*)d_in[10];
    float* out = (float*)d_out;

    gnn_kernel<<<32, 1024, 0, stream>>>(x, W1, b1, W2, b2, W3, b3,
                                        We1, be1, We2, be2, out);
}

// Round 2
// 15.830 us; speedup vs baseline: 1.5668x; 1.5668x over previous
//
#include <hip/hip_runtime.h>
#include <math.h>

#define NN 256
#define PP 32640        // N*(N-1)/2
#define HH 64
#define SPLIT 16        // scan blocks per batch
#define Q_PER (PP / 4 / SPLIT)   // 510 float4 per chunk
#define BB 32

// ---------------------------------------------------------------------------
// Kernel 1: per-(batch,chunk) scan. Each block scans 510 float4 of dec + ind,
// builds a private LDS degree histogram (pairs with dec==1 contribute to both
// endpoints), finds the one-hot index, and stores the 256-int partial
// histogram to its own workspace slot (plain stores — no init required).
// ---------------------------------------------------------------------------
__global__ __launch_bounds__(256) void gnn_scan(
    const float* __restrict__ x,
    int* __restrict__ ws_hist,   // [BB][SPLIT][NN]
    int* __restrict__ ws_cur)    // [BB]
{
    const int blk   = blockIdx.x;
    const int b     = blk / SPLIT;
    const int chunk = blk % SPLIT;
    const int tid   = threadIdx.x;

    __shared__ int deg[NN];
    deg[tid] = 0;
    __syncthreads();

    const float*  decp = x + (size_t)b * (2 * PP);
    const float4* dec4 = (const float4*)decp;
    const float4* ind4 = (const float4*)(decp + PP);

    const int qbase = chunk * Q_PER;
    for (int qq = tid; qq < Q_PER; qq += 256) {
        const int q  = qbase + qq;
        float4 d  = dec4[q];
        float4 iv = ind4[q];
        const int p0 = q * 4;

        // invert triu_indices once per float4: row i with O(i) <= p0,
        // O(i) = i*(511-i)/2 ; row i spans [O(i), O(i)+255-i)
        int i = (int)((511.0f - sqrtf(261121.0f - 8.0f * (float)p0)) * 0.5f);
        while (i * (511 - i) / 2 > p0) --i;
        while ((i + 1) * (510 - i) / 2 <= p0) ++i;
        int rowStart = i * (511 - i) / 2;

        float dv[4]  = {d.x, d.y, d.z, d.w};
        float ivv[4] = {iv.x, iv.y, iv.z, iv.w};
        #pragma unroll
        for (int u = 0; u < 4; ++u) {
            const int p = p0 + u;
            while (p - rowStart >= 255 - i) { ++i; rowStart = i * (511 - i) / 2; }
            if (ivv[u] > 0.5f) ws_cur[b] = p;     // one-hot: exactly one writer
            if (dv[u] == 1.0f) {
                const int j = i + 1 + (p - rowStart);
                atomicAdd(&deg[i], 1);
                atomicAdd(&deg[j], 1);
            }
        }
    }
    __syncthreads();

    ws_hist[(size_t)blk * NN + tid] = deg[tid];   // coalesced partial store
}

// ---------------------------------------------------------------------------
// Kernel 2: one block (single wave, 64 threads) per batch. Reduce the SPLIT
// partial histograms, derive (sumdeg, cntzero), then the collapsed network:
//   node features summed over 256 nodes: f0=sum(deg)/255, f1=#(deg==0), f2=2
//   g1 = relu((f @ W1)/256 + b1); g2 = relu(g1@W2+b2); g3 = relu(g2@W3+b3)
//   hm = relu([g3,g3,e0,e1,1] @ We1 + be1); out = sigmoid(hm@We2 + be2)
// ---------------------------------------------------------------------------
__global__ __launch_bounds__(64) void gnn_epilogue(
    const float* __restrict__ x,
    const float* __restrict__ W1, const float* __restrict__ b1,
    const float* __restrict__ W2, const float* __restrict__ b2,
    const float* __restrict__ W3, const float* __restrict__ b3,
    const float* __restrict__ We1, const float* __restrict__ be1,
    const float* __restrict__ We2, const float* __restrict__ be2,
    const int* __restrict__ ws_hist,
    const int* __restrict__ ws_cur,
    float* __restrict__ out)
{
    const int b   = blockIdx.x;
    const int tid = threadIdx.x;   // 0..63, exactly one wave

    __shared__ float g[HH];

    // each lane accumulates degrees of 4 nodes (int4, coalesced)
    int4 acc = {0, 0, 0, 0};
    for (int c = 0; c < SPLIT; ++c) {
        const int4* hp = (const int4*)(ws_hist + ((size_t)b * SPLIT + c) * NN);
        int4 v = hp[tid];
        acc.x += v.x; acc.y += v.y; acc.z += v.z; acc.w += v.w;
    }
    int sum = acc.x + acc.y + acc.z + acc.w;
    int zc  = (acc.x == 0) + (acc.y == 0) + (acc.z == 0) + (acc.w == 0);
    #pragma unroll
    for (int off = 32; off > 0; off >>= 1) {
        sum += __shfl_down(sum, off);
        zc  += __shfl_down(zc,  off);
    }
    sum = __shfl(sum, 0);
    zc  = __shfl(zc,  0);

    const float f0 = (float)sum * (1.0f / 255.0f);
    const float f1 = (float)zc;
    const float f2 = 2.0f;

    float s = f0 * W1[0 * HH + tid] + f1 * W1[1 * HH + tid] + f2 * W1[2 * HH + tid];
    g[tid] = fmaxf(s * (1.0f / 256.0f) + b1[tid], 0.0f);
    __syncthreads();

    s = b2[tid];
    #pragma unroll 8
    for (int k = 0; k < HH; ++k) s += g[k] * W2[k * HH + tid];
    const float g2v = fmaxf(s, 0.0f);
    __syncthreads();
    g[tid] = g2v;
    __syncthreads();

    s = b3[tid];
    #pragma unroll 8
    for (int k = 0; k < HH; ++k) s += g[k] * W3[k * HH + tid];
    const float g3v = fmaxf(s, 0.0f);
    __syncthreads();
    g[tid] = g3v;
    __syncthreads();

    const int   cur  = ws_cur[b];
    const float dcur = x[(size_t)b * (2 * PP) + cur];
    const float e0 = (dcur == 1.0f) ? 1.0f : 0.0f;
    const float e1 = (dcur != 0.5f) ? 1.0f : 0.0f;

    s = be1[tid];
    #pragma unroll 8
    for (int k = 0; k < HH; ++k)
        s += g[k] * (We1[k * HH + tid] + We1[(HH + k) * HH + tid]);
    s += e0 * We1[128 * HH + tid] + e1 * We1[129 * HH + tid] + We1[130 * HH + tid];
    const float hm = fmaxf(s, 0.0f);

    float contrib = hm * We2[tid];
    #pragma unroll
    for (int off = 32; off > 0; off >>= 1)
        contrib += __shfl_down(contrib, off);

    if (tid == 0) {
        const float logit = contrib + be2[0];
        const float sig = 1.0f / (1.0f + expf(-logit));
        out[b * 2 + 0] = sig;
        out[b * 2 + 1] = sig;
    }
}

extern "C" void kernel_launch(void* const* d_in, const int* in_sizes, int n_in,
                              void* d_out, int out_size, void* d_ws, size_t ws_size,
                              hipStream_t stream) {
    const float* x   = (const float*)d_in[0];
    const float* W1  = (const float*)d_in[1];
    const float* b1  = (const float*)d_in[2];
    const float* W2  = (const float*)d_in[3];
    const float* b2  = (const float*)d_in[4];
    const float* W3  = (const float*)d_in[5];
    const float* b3  = (const float*)d_in[6];
    const float* We1 = (const float*)d_in[7];
    const float* be1 = (const float*)d_in[8];
    const float* We2 = (const float*)d_in[9];
    const float* be2 = (const float*)d_in[10];
    float* out = (float*)d_out;

    int* ws_hist = (int*)d_ws;                           // BB*SPLIT*NN ints = 512 KB
    int* ws_cur  = (int*)((char*)d_ws + (size_t)BB * SPLIT * NN * sizeof(int));

    gnn_scan<<<BB * SPLIT, 256, 0, stream>>>(x, ws_hist, ws_cur);
    gnn_epilogue<<<BB, 64, 0, stream>>>(x, W1, b1, W2, b2, W3, b3,
                                        We1, be1, We2, be2,
                                        ws_hist, ws_cur, out);
}